// Round 1
// baseline (1782.334 us; speedup 1.0000x reference)
//
#include <hip/hip_runtime.h>
#include <hip/hip_fp16.h>
#include <cstdint>
#include <cstddef>

#define EMB    2048
#define MAXF   9216
#define HIDP   512
#define NBATCH 4
#define NSEQ   2048
#define MTOT   (NBATCH*NSEQ)   // 8192

typedef _Float16 f16;
typedef _Float16 half8_t  __attribute__((ext_vector_type(8)));
typedef float    float4_t __attribute__((ext_vector_type(4)));

// ---------------- workspace layout (bytes) ----------------
// x16   : 8192*2048*2  = 33,554,432
// gw16  : 9216*2048*2  = 37,748,736
// uw16  :                37,748,736
// hid16 : 8192*9216*2  = 150,994,944  (gate result, then hidden, in place)
// dw16  : overlays x16/gw16 region (converted AFTER the up pass)
// small : sumsq[8192]f32, meanx[8192]f32, hbuf[2048]f32, scalars
static const size_t OFF_X16   = 0;
static const size_t OFF_GW16  = 33554432;
static const size_t OFF_UW16  = 71303168;
static const size_t OFF_HID   = 109051904;
static const size_t OFF_DW16  = 0;
static const size_t OFF_SMALL = 260046848;   // total ws use ~248 MiB

// ---------------- small kernels ----------------
__global__ void k_zero(float* __restrict__ p, int n) {
    int i = blockIdx.x * blockDim.x + threadIdx.x;
    if (i < n) p[i] = 0.f;
}

__global__ void k_cast_f2h(const float* __restrict__ s, f16* __restrict__ d, int n8) {
    int i   = blockIdx.x * blockDim.x + threadIdx.x;
    int str = gridDim.x * blockDim.x;
    for (; i < n8; i += str) {
        const float4* p = (const float4*)(s + (size_t)i * 8);
        float4 a = p[0], b = p[1];
        half8_t h;
        h[0] = (f16)a.x; h[1] = (f16)a.y; h[2] = (f16)a.z; h[3] = (f16)a.w;
        h[4] = (f16)b.x; h[5] = (f16)b.y; h[6] = (f16)b.z; h[7] = (f16)b.w;
        *(half8_t*)(d + (size_t)i * 8) = h;
    }
}

// partial column sums of x over S (atomically accumulated into meanx; scaled later)
__global__ void k_meanpart(const float* __restrict__ x, float* __restrict__ meanx) {
    int bid = blockIdx.x;            // 256 blocks: b(4) x sc(8) x ec(8)
    int b  = bid >> 6;
    int sc = (bid >> 3) & 7;
    int ec = bid & 7;
    int e  = (ec << 8) + threadIdx.x;
    const float* p = x + (size_t)b * NSEQ * EMB + (size_t)(sc * 256) * EMB + e;
    float acc = 0.f;
    #pragma unroll 4
    for (int s2 = 0; s2 < 256; ++s2) acc += p[(size_t)s2 * EMB];
    atomicAdd(&meanx[b * EMB + e], acc);
}

// h = silu((meanx/S) @ w_pred1^T)  — one wave per (b, j)
__global__ void k_pred1(const float* __restrict__ meanx, const float* __restrict__ w1,
                        float* __restrict__ hbuf) {
    int g    = blockIdx.x * 4 + (threadIdx.x >> 6);  // 2048 waves
    int lane = threadIdx.x & 63;
    int b = g >> 9, j = g & 511;
    const float* mp = meanx + b * EMB;
    const float* wp = w1 + (size_t)j * EMB;
    float acc = 0.f;
    #pragma unroll 8
    for (int t = 0; t < 32; ++t) { int e = (t << 6) + lane; acc += mp[e] * wp[e]; }
    for (int o = 1; o < 64; o <<= 1) acc += __shfl_xor(acc, o);
    if (lane == 0) {
        float v = acc * (1.0f / (float)NSEQ);
        hbuf[(b << 9) + j] = v / (1.f + expf(-v));
    }
}

// dim predictor tail: sigmoid, ratio clip, mean over batch, n = floor(6144*mean)
__global__ void k_pred2(const float* __restrict__ hbuf, const float* __restrict__ w2,
                        float* __restrict__ scal_f, int* __restrict__ scal_i) {
    int lane = threadIdx.x & 63;
    float rs = 0.f;
    for (int b = 0; b < 4; ++b) {
        float a = 0.f;
        #pragma unroll
        for (int t = 0; t < 8; ++t) { int e = (t << 6) + lane; a += hbuf[(b << 9) + e] * w2[e]; }
        for (int o = 1; o < 64; o <<= 1) a += __shfl_xor(a, o);
        float r = 1.f / (1.f + expf(-a));
        float ratio = 1.0f + (r - 0.5f);            // *2*ADAPT with ADAPT=0.5
        ratio = fminf(fmaxf(ratio, 0.5f), 1.5f);
        rs += ratio;
    }
    float n = floorf(6144.0f * (rs * 0.25f));
    n = fminf(fmaxf(n, 1.0f), 9216.0f);
    if (threadIdx.x == 0) { scal_f[0] = n; scal_i[0] = (int)n; }
}

// ---------------- GEMM core (m97 structure: 128x128 tile, BK=64, 4 waves) ----------------
__device__ __forceinline__ void gload16(const f16* g, f16* l) {
    __builtin_amdgcn_global_load_lds((const __attribute__((address_space(1))) void*)g,
                                     (__attribute__((address_space(3))) void*)l, 16, 0, 0);
}

// LDS layout per tile: [k8(8)][row(128)] slots of 16B (8 halves) -> conflict-free ds_read_b128
template<int SA, int SB>
__device__ __forceinline__ void gemm_core(const f16* __restrict__ Ag, const f16* __restrict__ Bg,
                                          f16* As, f16* Bs,
                                          int mrow0, int ncol0, int kTiles,
                                          int wave, int lane, float4_t acc[4][4]) {
    const int wr = wave >> 1, wc = wave & 1;
    const int q  = lane >> 4, r = lane & 15;
    const bool stageA = (wave < 2);
    const int  iBase  = (wave & 1) << 3;
    const f16* Sg     = stageA ? Ag : Bg;
    const int  sbase0 = stageA ? mrow0 : ncol0;
    const int  sstr   = stageA ? SA : SB;
    f16*       Sl     = stageA ? As : Bs;

    for (int kt = 0; kt < kTiles; ++kt) {
        __syncthreads();                        // previous tile's compute done
        const int k0 = kt << 6;
        #pragma unroll
        for (int t = 0; t < 8; ++t) {           // 8 x 1KB per wave
            int i   = iBase + t;
            int k8  = i >> 1;
            int row = ((i & 1) << 6) + lane;
            gload16(Sg + (size_t)(sbase0 + row) * sstr + k0 + (k8 << 3), Sl + i * 512);
        }
        __syncthreads();                        // compiler drains vmcnt(0) before barrier
        #pragma unroll
        for (int ks = 0; ks < 2; ++ks) {
            half8_t af[4], bf[4];
            #pragma unroll
            for (int m = 0; m < 4; ++m)
                af[m] = *(const half8_t*)(As + ((((ks << 2) + q) << 7) + (wr << 6) + (m << 4) + r) * 8);
            #pragma unroll
            for (int nn = 0; nn < 4; ++nn)
                bf[nn] = *(const half8_t*)(Bs + ((((ks << 2) + q) << 7) + (wc << 6) + (nn << 4) + r) * 8);
            #pragma unroll
            for (int m = 0; m < 4; ++m)
                #pragma unroll
                for (int nn = 0; nn < 4; ++nn)
                    acc[m][nn] = __builtin_amdgcn_mfma_f32_16x16x32_f16(af[m], bf[nn], acc[m][nn], 0, 0, 0);
        }
    }
}

// gate pass: hid16 <- silu(x @ gate_w^T)  (fp16), skip column-blocks beyond n
__global__ __launch_bounds__(256) void k_gemm_gate(const f16* __restrict__ x16,
                                                   const f16* __restrict__ gw16,
                                                   f16* __restrict__ hid16,
                                                   const int* __restrict__ np) {
    __shared__ __align__(16) f16 As[8192];
    __shared__ __align__(16) f16 Bs[8192];
    const int nint = *np;
    const int ncol0 = blockIdx.x << 7;
    if (ncol0 >= nint) return;
    const int mrow0 = blockIdx.y << 7;
    const int wave = threadIdx.x >> 6, lane = threadIdx.x & 63;
    float4_t acc[4][4];
    const float4_t z = {0.f, 0.f, 0.f, 0.f};
    #pragma unroll
    for (int m = 0; m < 4; ++m)
        #pragma unroll
        for (int nn = 0; nn < 4; ++nn) acc[m][nn] = z;

    gemm_core<EMB, EMB>(x16, gw16, As, Bs, mrow0, ncol0, EMB / 64, wave, lane, acc);

    const int wr = wave >> 1, wc = wave & 1, q = lane >> 4, r = lane & 15;
    #pragma unroll
    for (int m = 0; m < 4; ++m)
        #pragma unroll
        for (int nn = 0; nn < 4; ++nn) {
            int col = ncol0 + (wc << 6) + (nn << 4) + r;
            #pragma unroll
            for (int j = 0; j < 4; ++j) {
                int grow = mrow0 + (wr << 6) + (m << 4) + (q << 2) + j;
                float v = acc[m][nn][j];
                hid16[(size_t)grow * MAXF + col] = (f16)(v / (1.f + expf(-v)));
            }
        }
}

// up pass: hidden = silu(gate)*up*mask (in place), += norm_w fold, rowwise sum(h^2) atomics
__global__ __launch_bounds__(256) void k_gemm_up(const f16* __restrict__ x16,
                                                 const f16* __restrict__ uw16,
                                                 f16* __restrict__ hid16,
                                                 const float* __restrict__ normw,
                                                 float* __restrict__ sumsq,
                                                 const int* __restrict__ np) {
    __shared__ __align__(16) f16 As[8192];
    __shared__ __align__(16) f16 Bs[8192];
    const int nint = *np;
    const int ncol0 = blockIdx.x << 7;
    if (ncol0 >= nint) return;
    const int mrow0 = blockIdx.y << 7;
    const int wave = threadIdx.x >> 6, lane = threadIdx.x & 63;
    float4_t acc[4][4];
    const float4_t z = {0.f, 0.f, 0.f, 0.f};
    #pragma unroll
    for (int m = 0; m < 4; ++m)
        #pragma unroll
        for (int nn = 0; nn < 4; ++nn) acc[m][nn] = z;

    gemm_core<EMB, EMB>(x16, uw16, As, Bs, mrow0, ncol0, EMB / 64, wave, lane, acc);

    const int wr = wave >> 1, wc = wave & 1, q = lane >> 4, r = lane & 15;
    #pragma unroll
    for (int m = 0; m < 4; ++m)
        #pragma unroll
        for (int j = 0; j < 4; ++j) {
            int grow = mrow0 + (wr << 6) + (m << 4) + (q << 2) + j;
            float ssq = 0.f;
            #pragma unroll
            for (int nn = 0; nn < 4; ++nn) {
                int col = ncol0 + (wc << 6) + (nn << 4) + r;
                size_t idx = (size_t)grow * MAXF + col;
                float v = 0.f;
                if (col < nint) {
                    float g = (float)hid16[idx];
                    v = g * acc[m][nn][j];
                    ssq += v * v;
                    v *= normw[col];
                }
                hid16[idx] = (f16)v;
            }
            ssq += __shfl_xor(ssq, 1);
            ssq += __shfl_xor(ssq, 2);
            ssq += __shfl_xor(ssq, 4);
            ssq += __shfl_xor(ssq, 8);
            if (r == 0) atomicAdd(&sumsq[grow], ssq);
        }
}

// down pass: out = (hidden @ down_w^T) * (1/rms_row), K bounded by ceil(n/64)
__global__ __launch_bounds__(256) void k_gemm_down(const f16* __restrict__ hid16,
                                                   const f16* __restrict__ dw16,
                                                   float* __restrict__ out,
                                                   const float* __restrict__ sumsq,
                                                   const float* __restrict__ nfp,
                                                   const int* __restrict__ np) {
    __shared__ __align__(16) f16 As[8192];
    __shared__ __align__(16) f16 Bs[8192];
    const int nint = *np;
    const float nf = *nfp;
    const int kT = (nint + 63) >> 6;
    const int ncol0 = blockIdx.x << 7;     // e dimension (2048 -> 16 blocks)
    const int mrow0 = blockIdx.y << 7;
    const int wave = threadIdx.x >> 6, lane = threadIdx.x & 63;
    float4_t acc[4][4];
    const float4_t z = {0.f, 0.f, 0.f, 0.f};
    #pragma unroll
    for (int m = 0; m < 4; ++m)
        #pragma unroll
        for (int nn = 0; nn < 4; ++nn) acc[m][nn] = z;

    gemm_core<MAXF, MAXF>(hid16, dw16, As, Bs, mrow0, ncol0, kT, wave, lane, acc);

    const int wr = wave >> 1, wc = wave & 1, q = lane >> 4, r = lane & 15;
    #pragma unroll
    for (int m = 0; m < 4; ++m)
        #pragma unroll
        for (int j = 0; j < 4; ++j) {
            int grow = mrow0 + (wr << 6) + (m << 4) + (q << 2) + j;
            float rms = sqrtf(sumsq[grow] / nf + 1e-6f);
            rms = fminf(fmaxf(rms, 1e-6f), 1e6f);
            float inv = 1.f / rms;
            #pragma unroll
            for (int nn = 0; nn < 4; ++nn) {
                int col = ncol0 + (wc << 6) + (nn << 4) + r;
                out[(size_t)grow * EMB + col] = acc[m][nn][j] * inv;
            }
        }
}

// ---------------- launch ----------------
extern "C" void kernel_launch(void* const* d_in, const int* in_sizes, int n_in,
                              void* d_out, int out_size, void* d_ws, size_t ws_size,
                              hipStream_t stream) {
    (void)in_sizes; (void)n_in; (void)out_size; (void)ws_size;
    const float* x  = (const float*)d_in[0];
    const float* w1 = (const float*)d_in[1];
    const float* w2 = (const float*)d_in[2];
    const float* gw = (const float*)d_in[3];
    const float* uw = (const float*)d_in[4];
    const float* dw = (const float*)d_in[5];
    const float* nw = (const float*)d_in[6];
    float* out = (float*)d_out;
    char* ws = (char*)d_ws;

    f16* x16   = (f16*)(ws + OFF_X16);
    f16* gw16  = (f16*)(ws + OFF_GW16);
    f16* uw16  = (f16*)(ws + OFF_UW16);
    f16* hid16 = (f16*)(ws + OFF_HID);
    f16* dw16  = (f16*)(ws + OFF_DW16);
    float* sumsq  = (float*)(ws + OFF_SMALL);
    float* meanx  = (float*)(ws + OFF_SMALL + 32768);
    float* hbuf   = (float*)(ws + OFF_SMALL + 65536);
    float* scal_f = (float*)(ws + OFF_SMALL + 73728);
    int*   scal_i = (int*)(ws + OFF_SMALL + 73728 + 4);

    // zero accumulators (sumsq + meanx are contiguous: 16384 floats)
    k_zero<<<64, 256, 0, stream>>>(sumsq, 16384);

    // fp32 -> fp16 conversions
    k_cast_f2h<<<1024, 256, 0, stream>>>(x,  x16,  (MTOT * EMB) / 8);
    k_cast_f2h<<<1024, 256, 0, stream>>>(gw, gw16, (MAXF * EMB) / 8);
    k_cast_f2h<<<1024, 256, 0, stream>>>(uw, uw16, (MAXF * EMB) / 8);

    // dim predictor (fp32, exact-path)
    k_meanpart<<<256, 256, 0, stream>>>(x, meanx);
    k_pred1<<<512, 256, 0, stream>>>(meanx, w1, hbuf);
    k_pred2<<<1, 64, 0, stream>>>(hbuf, w2, scal_f, scal_i);

    // FFN
    k_gemm_gate<<<dim3(72, 64), 256, 0, stream>>>(x16, gw16, hid16, scal_i);
    k_gemm_up<<<dim3(72, 64), 256, 0, stream>>>(x16, uw16, hid16, nw, sumsq, scal_i);
    k_cast_f2h<<<1024, 256, 0, stream>>>(dw, dw16, (EMB * MAXF) / 8);   // overlays dead x16/gw16
    k_gemm_down<<<dim3(16, 64), 256, 0, stream>>>(hid16, dw16, out, sumsq, scal_f, scal_i);
}

// Round 2
// 1710.686 us; speedup vs baseline: 1.0419x; 1.0419x over previous
//
#include <hip/hip_runtime.h>
#include <hip/hip_fp16.h>
#include <cstdint>
#include <cstddef>

#define EMB    2048
#define MAXF   9216
#define NBATCH 4
#define NSEQ   2048
#define MTOT   (NBATCH*NSEQ)   // 8192

typedef _Float16 f16;
typedef _Float16 half8_t  __attribute__((ext_vector_type(8)));
typedef float    float4_t __attribute__((ext_vector_type(4)));

// ---------------- workspace layout (bytes) ----------------
static const size_t OFF_X16   = 0;
static const size_t OFF_GW16  = 33554432;
static const size_t OFF_UW16  = 71303168;
static const size_t OFF_HID   = 109051904;
static const size_t OFF_DW16  = 0;           // overlays x16/gw16 after fused pass
static const size_t OFF_SMALL = 260046848;

// ---------------- small kernels ----------------
__global__ void k_zero(float* __restrict__ p, int n) {
    int i = blockIdx.x * blockDim.x + threadIdx.x;
    if (i < n) p[i] = 0.f;
}

__global__ void k_cast_f2h(const float* __restrict__ s, f16* __restrict__ d, int n8) {
    int i   = blockIdx.x * blockDim.x + threadIdx.x;
    int str = gridDim.x * blockDim.x;
    for (; i < n8; i += str) {
        const float4* p = (const float4*)(s + (size_t)i * 8);
        float4 a = p[0], b = p[1];
        half8_t h;
        h[0] = (f16)a.x; h[1] = (f16)a.y; h[2] = (f16)a.z; h[3] = (f16)a.w;
        h[4] = (f16)b.x; h[5] = (f16)b.y; h[6] = (f16)b.z; h[7] = (f16)b.w;
        *(half8_t*)(d + (size_t)i * 8) = h;
    }
}

__global__ void k_meanpart(const float* __restrict__ x, float* __restrict__ meanx) {
    int bid = blockIdx.x;            // 256 blocks: b(4) x sc(8) x ec(8)
    int b  = bid >> 6;
    int sc = (bid >> 3) & 7;
    int ec = bid & 7;
    int e  = (ec << 8) + threadIdx.x;
    const float* p = x + (size_t)b * NSEQ * EMB + (size_t)(sc * 256) * EMB + e;
    float acc = 0.f;
    #pragma unroll 4
    for (int s2 = 0; s2 < 256; ++s2) acc += p[(size_t)s2 * EMB];
    atomicAdd(&meanx[b * EMB + e], acc);
}

__global__ void k_pred1(const float* __restrict__ meanx, const float* __restrict__ w1,
                        float* __restrict__ hbuf) {
    int g    = blockIdx.x * 4 + (threadIdx.x >> 6);  // 2048 waves
    int lane = threadIdx.x & 63;
    int b = g >> 9, j = g & 511;
    const float* mp = meanx + b * EMB;
    const float* wp = w1 + (size_t)j * EMB;
    float acc = 0.f;
    #pragma unroll 8
    for (int t = 0; t < 32; ++t) { int e = (t << 6) + lane; acc += mp[e] * wp[e]; }
    for (int o = 1; o < 64; o <<= 1) acc += __shfl_xor(acc, o);
    if (lane == 0) {
        float v = acc * (1.0f / (float)NSEQ);
        hbuf[(b << 9) + j] = v / (1.f + expf(-v));
    }
}

__global__ void k_pred2(const float* __restrict__ hbuf, const float* __restrict__ w2,
                        float* __restrict__ scal_f, int* __restrict__ scal_i) {
    int lane = threadIdx.x & 63;
    float rs = 0.f;
    for (int b = 0; b < 4; ++b) {
        float a = 0.f;
        #pragma unroll
        for (int t = 0; t < 8; ++t) { int e = (t << 6) + lane; a += hbuf[(b << 9) + e] * w2[e]; }
        for (int o = 1; o < 64; o <<= 1) a += __shfl_xor(a, o);
        float r = 1.f / (1.f + expf(-a));
        float ratio = 1.0f + (r - 0.5f);            // *2*ADAPT with ADAPT=0.5
        ratio = fminf(fmaxf(ratio, 0.5f), 1.5f);
        rs += ratio;
    }
    float n = floorf(6144.0f * (rs * 0.25f));
    n = fminf(fmaxf(n, 1.0f), 9216.0f);
    if (threadIdx.x == 0) { scal_f[0] = n; scal_i[0] = (int)n; }
}

// ---------------- staging helper ----------------
__device__ __forceinline__ void gload16(const f16* g, f16* l) {
    __builtin_amdgcn_global_load_lds((const __attribute__((address_space(1))) void*)g,
                                     (__attribute__((address_space(3))) void*)l, 16, 0, 0);
}

// ---------------- fused gate+up GEMM: 128x128 tile, BK=64, 8 waves (2M x 4N) ----------------
// hid16 <- silu(x@gw^T) * (x@uw^T) * mask * norm_w  (fp16); sumsq[row] += h^2 (pre-norm_w)
__global__ __launch_bounds__(512, 4) void k_gemm_fused(const f16* __restrict__ x16,
                                                       const f16* __restrict__ gw16,
                                                       const f16* __restrict__ uw16,
                                                       f16* __restrict__ hid16,
                                                       const float* __restrict__ normw,
                                                       float* __restrict__ sumsq,
                                                       const int* __restrict__ np) {
    __shared__ __align__(16) f16 As[8192];   // [k8(8)][row(128)][8 halves]
    __shared__ __align__(16) f16 Bgs[8192];
    __shared__ __align__(16) f16 Bus[8192];
    const int nint = *np;
    const int ncol0 = blockIdx.x << 7;
    if (ncol0 >= nint) return;
    const int mrow0 = blockIdx.y << 7;
    const int wave = threadIdx.x >> 6, lane = threadIdx.x & 63;
    const int wr = wave >> 2, wc = wave & 3;       // 2M x 4N -> per-wave 64x32 per matrix
    const int q = lane >> 4, r = lane & 15;

    float4_t acc_g[4][2], acc_u[4][2];
    const float4_t z = {0.f, 0.f, 0.f, 0.f};
    #pragma unroll
    for (int m = 0; m < 4; ++m)
        #pragma unroll
        for (int nn = 0; nn < 2; ++nn) { acc_g[m][nn] = z; acc_u[m][nn] = z; }

    for (int kt = 0; kt < EMB / 64; ++kt) {
        __syncthreads();                        // previous tile's compute done
        const int k0 = kt << 6;
        #pragma unroll
        for (int t = 0; t < 6; ++t) {           // 48 slot-loads / 8 waves = 6 each
            int s    = wave * 6 + t;
            int tile = s >> 4;                  // 0=A, 1=Bg, 2=Bu
            int j    = s & 15;
            int k8   = j >> 1;
            int row  = ((j & 1) << 6) + lane;
            const f16* src = (tile == 0) ? (x16  + (size_t)(mrow0 + row) * EMB)
                           : (tile == 1) ? (gw16 + (size_t)(ncol0 + row) * EMB)
                                         : (uw16 + (size_t)(ncol0 + row) * EMB);
            f16* dst = ((tile == 0) ? As : (tile == 1) ? Bgs : Bus) + j * 512;
            gload16(src + k0 + (k8 << 3), dst);
        }
        __syncthreads();                        // vmcnt(0) drain before compute
        #pragma unroll
        for (int ks = 0; ks < 2; ++ks) {
            half8_t af[4], bg[2], bu[2];
            #pragma unroll
            for (int m = 0; m < 4; ++m)
                af[m] = *(const half8_t*)(As + ((((ks << 2) + q) << 7) + (wr << 6) + (m << 4) + r) * 8);
            #pragma unroll
            for (int nn = 0; nn < 2; ++nn) {
                int brow = (((ks << 2) + q) << 7) + (wc << 5) + (nn << 4) + r;
                bg[nn] = *(const half8_t*)(Bgs + brow * 8);
                bu[nn] = *(const half8_t*)(Bus + brow * 8);
            }
            #pragma unroll
            for (int m = 0; m < 4; ++m)
                #pragma unroll
                for (int nn = 0; nn < 2; ++nn) {
                    acc_g[m][nn] = __builtin_amdgcn_mfma_f32_16x16x32_f16(af[m], bg[nn], acc_g[m][nn], 0, 0, 0);
                    acc_u[m][nn] = __builtin_amdgcn_mfma_f32_16x16x32_f16(af[m], bu[nn], acc_u[m][nn], 0, 0, 0);
                }
        }
    }

    // epilogue: h = silu(g)*u (masked), ssq per row, store h*norm_w as fp16
    #pragma unroll
    for (int m = 0; m < 4; ++m)
        #pragma unroll
        for (int j = 0; j < 4; ++j) {
            int grow = mrow0 + (wr << 6) + (m << 4) + (q << 2) + j;
            float ssq = 0.f;
            #pragma unroll
            for (int nn = 0; nn < 2; ++nn) {
                int col = ncol0 + (wc << 5) + (nn << 4) + r;
                float v = 0.f;
                if (col < nint) {
                    float g = acc_g[m][nn][j];
                    float sg = g / (1.f + expf(-g));
                    v = sg * acc_u[m][nn][j];
                    ssq += v * v;
                    v *= normw[col];
                }
                hid16[(size_t)grow * MAXF + col] = (f16)v;
            }
            ssq += __shfl_xor(ssq, 1);
            ssq += __shfl_xor(ssq, 2);
            ssq += __shfl_xor(ssq, 4);
            ssq += __shfl_xor(ssq, 8);
            if (r == 0) atomicAdd(&sumsq[grow], ssq);
        }
}

// ---------------- down GEMM (m97 structure: 128x128 tile, BK=64, 4 waves) ----------------
template<int SA, int SB>
__device__ __forceinline__ void gemm_core(const f16* __restrict__ Ag, const f16* __restrict__ Bg,
                                          f16* As, f16* Bs,
                                          int mrow0, int ncol0, int kTiles,
                                          int wave, int lane, float4_t acc[4][4]) {
    const int wr = wave >> 1, wc = wave & 1;
    const int q  = lane >> 4, r = lane & 15;
    const bool stageA = (wave < 2);
    const int  iBase  = (wave & 1) << 3;
    const f16* Sg     = stageA ? Ag : Bg;
    const int  sbase0 = stageA ? mrow0 : ncol0;
    const int  sstr   = stageA ? SA : SB;
    f16*       Sl     = stageA ? As : Bs;

    for (int kt = 0; kt < kTiles; ++kt) {
        __syncthreads();
        const int k0 = kt << 6;
        #pragma unroll
        for (int t = 0; t < 8; ++t) {
            int i   = iBase + t;
            int k8  = i >> 1;
            int row = ((i & 1) << 6) + lane;
            gload16(Sg + (size_t)(sbase0 + row) * sstr + k0 + (k8 << 3), Sl + i * 512);
        }
        __syncthreads();
        #pragma unroll
        for (int ks = 0; ks < 2; ++ks) {
            half8_t af[4], bf[4];
            #pragma unroll
            for (int m = 0; m < 4; ++m)
                af[m] = *(const half8_t*)(As + ((((ks << 2) + q) << 7) + (wr << 6) + (m << 4) + r) * 8);
            #pragma unroll
            for (int nn = 0; nn < 4; ++nn)
                bf[nn] = *(const half8_t*)(Bs + ((((ks << 2) + q) << 7) + (wc << 6) + (nn << 4) + r) * 8);
            #pragma unroll
            for (int m = 0; m < 4; ++m)
                #pragma unroll
                for (int nn = 0; nn < 4; ++nn)
                    acc[m][nn] = __builtin_amdgcn_mfma_f32_16x16x32_f16(af[m], bf[nn], acc[m][nn], 0, 0, 0);
        }
    }
}

__global__ __launch_bounds__(256) void k_gemm_down(const f16* __restrict__ hid16,
                                                   const f16* __restrict__ dw16,
                                                   float* __restrict__ out,
                                                   const float* __restrict__ sumsq,
                                                   const float* __restrict__ nfp,
                                                   const int* __restrict__ np) {
    __shared__ __align__(16) f16 As[8192];
    __shared__ __align__(16) f16 Bs[8192];
    const int nint = *np;
    const float nf = *nfp;
    const int kT = (nint + 63) >> 6;
    const int ncol0 = blockIdx.x << 7;     // e dimension (2048 -> 16 blocks)
    const int mrow0 = blockIdx.y << 7;
    const int wave = threadIdx.x >> 6, lane = threadIdx.x & 63;
    float4_t acc[4][4];
    const float4_t z = {0.f, 0.f, 0.f, 0.f};
    #pragma unroll
    for (int m = 0; m < 4; ++m)
        #pragma unroll
        for (int nn = 0; nn < 4; ++nn) acc[m][nn] = z;

    gemm_core<MAXF, MAXF>(hid16, dw16, As, Bs, mrow0, ncol0, kT, wave, lane, acc);

    const int wr = wave >> 1, wc = wave & 1, q = lane >> 4, r = lane & 15;
    #pragma unroll
    for (int m = 0; m < 4; ++m)
        #pragma unroll
        for (int j = 0; j < 4; ++j) {
            int grow = mrow0 + (wr << 6) + (m << 4) + (q << 2) + j;
            float rms = sqrtf(sumsq[grow] / nf + 1e-6f);
            rms = fminf(fmaxf(rms, 1e-6f), 1e6f);
            float inv = 1.f / rms;
            #pragma unroll
            for (int nn = 0; nn < 4; ++nn) {
                int col = ncol0 + (wc << 6) + (nn << 4) + r;
                out[(size_t)grow * EMB + col] = acc[m][nn][j] * inv;
            }
        }
}

// ---------------- launch ----------------
extern "C" void kernel_launch(void* const* d_in, const int* in_sizes, int n_in,
                              void* d_out, int out_size, void* d_ws, size_t ws_size,
                              hipStream_t stream) {
    (void)in_sizes; (void)n_in; (void)out_size; (void)ws_size;
    const float* x  = (const float*)d_in[0];
    const float* w1 = (const float*)d_in[1];
    const float* w2 = (const float*)d_in[2];
    const float* gw = (const float*)d_in[3];
    const float* uw = (const float*)d_in[4];
    const float* dw = (const float*)d_in[5];
    const float* nw = (const float*)d_in[6];
    float* out = (float*)d_out;
    char* ws = (char*)d_ws;

    f16* x16   = (f16*)(ws + OFF_X16);
    f16* gw16  = (f16*)(ws + OFF_GW16);
    f16* uw16  = (f16*)(ws + OFF_UW16);
    f16* hid16 = (f16*)(ws + OFF_HID);
    f16* dw16  = (f16*)(ws + OFF_DW16);
    float* sumsq  = (float*)(ws + OFF_SMALL);
    float* meanx  = (float*)(ws + OFF_SMALL + 32768);
    float* hbuf   = (float*)(ws + OFF_SMALL + 65536);
    float* scal_f = (float*)(ws + OFF_SMALL + 73728);
    int*   scal_i = (int*)(ws + OFF_SMALL + 73728 + 4);

    // zero accumulators (sumsq + meanx contiguous: 16384 floats)
    k_zero<<<64, 256, 0, stream>>>(sumsq, 16384);

    // fp32 -> fp16 conversions
    k_cast_f2h<<<1024, 256, 0, stream>>>(x,  x16,  (MTOT * EMB) / 8);
    k_cast_f2h<<<1024, 256, 0, stream>>>(gw, gw16, (MAXF * EMB) / 8);
    k_cast_f2h<<<1024, 256, 0, stream>>>(uw, uw16, (MAXF * EMB) / 8);

    // dim predictor (fp32, exact-path)
    k_meanpart<<<256, 256, 0, stream>>>(x, meanx);
    k_pred1<<<512, 256, 0, stream>>>(meanx, w1, hbuf);
    k_pred2<<<1, 64, 0, stream>>>(hbuf, w2, scal_f, scal_i);

    // fused gate+up SwiGLU
    k_gemm_fused<<<dim3(72, 64), 512, 0, stream>>>(x16, gw16, uw16, hid16, nw, sumsq, scal_i);

    // down projection
    k_cast_f2h<<<1024, 256, 0, stream>>>(dw, dw16, (EMB * MAXF) / 8);   // overlays dead x16/gw16
    k_gemm_down<<<dim3(16, 64), 256, 0, stream>>>(hid16, dw16, out, sumsq, scal_f, scal_i);
}